// Round 9
// baseline (106.818 us; speedup 1.0000x reference)
//
#include <hip/hip_runtime.h>

// N_RNA=20000, N_PROT=5000, D=128, C=4, E=500000
#define DIM 128
#define NCLS 4

typedef _Float16 f16x2 __attribute__((ext_vector_type(2)));
typedef _Float16 f16x4 __attribute__((ext_vector_type(4)));
typedef _Float16 f16x8 __attribute__((ext_vector_type(8)));

// ---------- merged fp32 -> fp16 conversion (both tables, one launch) ----------
__global__ __launch_bounds__(256) void cvt_both_kernel(
    const float* __restrict__ s1, _Float16* __restrict__ d1, int n1,
    const float* __restrict__ s2, _Float16* __restrict__ d2, int n2)
{
    const int total = n1 + n2;
    int i = (blockIdx.x * blockDim.x + threadIdx.x) * 8;
    const int stride = gridDim.x * blockDim.x * 8;
    for (; i < total; i += stride) {
        const float* s; _Float16* d; int j;
        if (i < n1) { s = s1; d = d1; j = i; }
        else        { s = s2; d = d2; j = i - n1; }
        const float4 a = *(const float4*)(s + j);
        const float4 b = *(const float4*)(s + j + 4);
        f16x8 o;
        o[0] = (_Float16)a.x; o[1] = (_Float16)a.y;
        o[2] = (_Float16)a.z; o[3] = (_Float16)a.w;
        o[4] = (_Float16)b.x; o[5] = (_Float16)b.y;
        o[6] = (_Float16)b.z; o[7] = (_Float16)b.w;
        *(f16x8*)(d + j) = o;
    }
}

// ---------- helpers ----------
// 4-partials -> 1 value/lane over 32 lanes in 6 shuffles.
// Output: lane l holds sum for class cls(l)=2*(l&1)+((l>>1)&1).
__device__ __forceinline__ float reduce4(float b0, float b1, float b2, float b3, int lane)
{
    const bool lo1 = (lane & 1) == 0;
    float k0 = lo1 ? b0 : b2, s0 = lo1 ? b2 : b0;
    float k1 = lo1 ? b1 : b3, s1 = lo1 ? b3 : b1;
    float v0 = k0 + __shfl_xor(s0, 1, 32);
    float v1 = k1 + __shfl_xor(s1, 1, 32);
    const bool lo2 = (lane & 2) == 0;
    float k = lo2 ? v0 : v1, s = lo2 ? v1 : v0;
    float v = k + __shfl_xor(s, 2, 32);
    v += __shfl_xor(v, 4, 32);
    v += __shfl_xor(v, 8, 32);
    v += __shfl_xor(v, 16, 32);
    return v;
}

// Per-edge: q = r .* p (packed f16), 4 class-dots via v_dot2_f32_f16, reduce, store.
__device__ __forceinline__ void dot_store(
    f16x4 r, f16x4 p, const f16x2 (&wl)[4], const f16x2 (&wh)[4],
    int lane, int cls, float* __restrict__ out, int e)
{
    const f16x4 q = r * p;                       // 2x v_pk_mul_f16
    const f16x2 ql = {q[0], q[1]};
    const f16x2 qh = {q[2], q[3]};
    const float b0 = __builtin_amdgcn_fdot2(ql, wl[0], __builtin_amdgcn_fdot2(qh, wh[0], 0.0f, false), false);
    const float b1 = __builtin_amdgcn_fdot2(ql, wl[1], __builtin_amdgcn_fdot2(qh, wh[1], 0.0f, false), false);
    const float b2 = __builtin_amdgcn_fdot2(ql, wl[2], __builtin_amdgcn_fdot2(qh, wh[2], 0.0f, false), false);
    const float b3 = __builtin_amdgcn_fdot2(ql, wl[3], __builtin_amdgcn_fdot2(qh, wh[3], 0.0f, false), false);
    const float v = reduce4(b0, b1, b2, b3, lane);
    if (lane < 4) out[(size_t)e * NCLS + cls] = fmaxf(v, 0.0f);
}

// ---------- decoder: ILP=12 edges/half-wave, 24 row loads in flight ----------
__global__ __launch_bounds__(256, 4) void decoder_ilp12_kernel(
    const _Float16* __restrict__ rna,   // [N_RNA, D] f16
    const _Float16* __restrict__ prot,  // [N_PROT, D] f16
    const int*   __restrict__ ridx,
    const int*   __restrict__ pidx,
    const float* __restrict__ wrel,
    const float* __restrict__ wcls,
    float*       __restrict__ out,
    int nEdges)                          // requires nEdges >= 4
{
    const int l32 = threadIdx.x & 31;
    const int hw  = (blockIdx.x * blockDim.x + threadIdx.x) >> 5;
    const int nhw = (gridDim.x * blockDim.x) >> 5;

    // Fused weights wf_j[d] = sum_c wrel[c,d]*wcls[c,j]; lane slice d = l32*4..+3,
    // held as f16x2 pairs for v_dot2_f32_f16.
    const float4 w0 = *(const float4*)(wrel + 0 * DIM + l32 * 4);
    const float4 w1 = *(const float4*)(wrel + 1 * DIM + l32 * 4);
    const float4 w2 = *(const float4*)(wrel + 2 * DIM + l32 * 4);
    const float4 w3 = *(const float4*)(wrel + 3 * DIM + l32 * 4);
    float wc[16];
#pragma unroll
    for (int i = 0; i < 16; ++i) wc[i] = wcls[i];
    f16x2 wl[4], wh[4];
#pragma unroll
    for (int j = 0; j < 4; ++j) {
        const float x = wc[j] * w0.x + wc[4 + j] * w1.x + wc[8 + j] * w2.x + wc[12 + j] * w3.x;
        const float y = wc[j] * w0.y + wc[4 + j] * w1.y + wc[8 + j] * w2.y + wc[12 + j] * w3.y;
        const float z = wc[j] * w0.z + wc[4 + j] * w1.z + wc[8 + j] * w2.z + wc[12 + j] * w3.z;
        const float w = wc[j] * w0.w + wc[4 + j] * w1.w + wc[8 + j] * w2.w + wc[12 + j] * w3.w;
        wl[j][0] = (_Float16)x; wl[j][1] = (_Float16)y;
        wh[j][0] = (_Float16)z; wh[j][1] = (_Float16)w;
    }
    const int cls = ((l32 & 1) << 1) | ((l32 >> 1) & 1);

    const long step = (long)nhw * 12;
    long e0 = (long)hw * 12;
    if (e0 >= nEdges) return;

    // Group bases (clamped so every loaded/stored edge is in range; duplicate
    // edges across clamped groups store identical values -> benign).
    int gb0 = (e0 + 3  >= nEdges) ? nEdges - 4 : (int)e0;
    int gb1 = (e0 + 7  >= nEdges) ? nEdges - 4 : (int)(e0 + 4);
    int gb2 = (e0 + 11 >= nEdges) ? nEdges - 4 : (int)(e0 + 8);

    int4 ri0 = *(const int4*)(ridx + gb0);
    int4 pi0 = *(const int4*)(pidx + gb0);
    int4 ri1 = *(const int4*)(ridx + gb1);
    int4 pi1 = *(const int4*)(pidx + gb1);
    int4 ri2 = *(const int4*)(ridx + gb2);
    int4 pi2 = *(const int4*)(pidx + gb2);

    for (;;) {
        // ---- issue all 24 row loads back-to-back (24 outstanding vmem) ----
        const f16x4 rA0 = ((const f16x4*)(rna + (size_t)ri0.x * DIM))[l32];
        const f16x4 rA1 = ((const f16x4*)(rna + (size_t)ri0.y * DIM))[l32];
        const f16x4 rA2 = ((const f16x4*)(rna + (size_t)ri0.z * DIM))[l32];
        const f16x4 rA3 = ((const f16x4*)(rna + (size_t)ri0.w * DIM))[l32];
        const f16x4 pA0 = ((const f16x4*)(prot + (size_t)pi0.x * DIM))[l32];
        const f16x4 pA1 = ((const f16x4*)(prot + (size_t)pi0.y * DIM))[l32];
        const f16x4 pA2 = ((const f16x4*)(prot + (size_t)pi0.z * DIM))[l32];
        const f16x4 pA3 = ((const f16x4*)(prot + (size_t)pi0.w * DIM))[l32];
        const f16x4 rB0 = ((const f16x4*)(rna + (size_t)ri1.x * DIM))[l32];
        const f16x4 rB1 = ((const f16x4*)(rna + (size_t)ri1.y * DIM))[l32];
        const f16x4 rB2 = ((const f16x4*)(rna + (size_t)ri1.z * DIM))[l32];
        const f16x4 rB3 = ((const f16x4*)(rna + (size_t)ri1.w * DIM))[l32];
        const f16x4 pB0 = ((const f16x4*)(prot + (size_t)pi1.x * DIM))[l32];
        const f16x4 pB1 = ((const f16x4*)(prot + (size_t)pi1.y * DIM))[l32];
        const f16x4 pB2 = ((const f16x4*)(prot + (size_t)pi1.z * DIM))[l32];
        const f16x4 pB3 = ((const f16x4*)(prot + (size_t)pi1.w * DIM))[l32];
        const f16x4 rC0 = ((const f16x4*)(rna + (size_t)ri2.x * DIM))[l32];
        const f16x4 rC1 = ((const f16x4*)(rna + (size_t)ri2.y * DIM))[l32];
        const f16x4 rC2 = ((const f16x4*)(rna + (size_t)ri2.z * DIM))[l32];
        const f16x4 rC3 = ((const f16x4*)(rna + (size_t)ri2.w * DIM))[l32];
        const f16x4 pC0 = ((const f16x4*)(prot + (size_t)pi2.x * DIM))[l32];
        const f16x4 pC1 = ((const f16x4*)(prot + (size_t)pi2.y * DIM))[l32];
        const f16x4 pC2 = ((const f16x4*)(prot + (size_t)pi2.z * DIM))[l32];
        const f16x4 pC3 = ((const f16x4*)(prot + (size_t)pi2.w * DIM))[l32];

        // ---- next iteration's indices (index regs already consumed) ----
        const long en = e0 + step;
        const bool more = en < nEdges;
        int ngb0 = gb0, ngb1 = gb1, ngb2 = gb2;
        if (more) {
            ngb0 = (en + 3  >= nEdges) ? nEdges - 4 : (int)en;
            ngb1 = (en + 7  >= nEdges) ? nEdges - 4 : (int)(en + 4);
            ngb2 = (en + 11 >= nEdges) ? nEdges - 4 : (int)(en + 8);
            ri0 = *(const int4*)(ridx + ngb0);
            pi0 = *(const int4*)(pidx + ngb0);
            ri1 = *(const int4*)(ridx + ngb1);
            pi1 = *(const int4*)(pidx + ngb1);
            ri2 = *(const int4*)(ridx + ngb2);
            pi2 = *(const int4*)(pidx + ngb2);
        }

        // ---- compute + store (vmcnt drains progressively) ----
        dot_store(rA0, pA0, wl, wh, l32, cls, out, gb0 + 0);
        dot_store(rA1, pA1, wl, wh, l32, cls, out, gb0 + 1);
        dot_store(rA2, pA2, wl, wh, l32, cls, out, gb0 + 2);
        dot_store(rA3, pA3, wl, wh, l32, cls, out, gb0 + 3);
        dot_store(rB0, pB0, wl, wh, l32, cls, out, gb1 + 0);
        dot_store(rB1, pB1, wl, wh, l32, cls, out, gb1 + 1);
        dot_store(rB2, pB2, wl, wh, l32, cls, out, gb1 + 2);
        dot_store(rB3, pB3, wl, wh, l32, cls, out, gb1 + 3);
        dot_store(rC0, pC0, wl, wh, l32, cls, out, gb2 + 0);
        dot_store(rC1, pC1, wl, wh, l32, cls, out, gb2 + 1);
        dot_store(rC2, pC2, wl, wh, l32, cls, out, gb2 + 2);
        dot_store(rC3, pC3, wl, wh, l32, cls, out, gb2 + 3);

        if (!more) break;
        e0 = en;
        gb0 = ngb0; gb1 = ngb1; gb2 = ngb2;
    }
}

// ---------- fp32 fallback (handles any shape / tiny workspace) ----------
__global__ __launch_bounds__(256) void decoder_f32_kernel(
    const float* __restrict__ rna, const float* __restrict__ prot,
    const int* __restrict__ ridx, const int* __restrict__ pidx,
    const float* __restrict__ wrel, const float* __restrict__ wcls,
    float* __restrict__ out, int nEdges)
{
    const int lane32 = threadIdx.x & 31;
    const int hw     = (blockIdx.x * blockDim.x + threadIdx.x) >> 5;
    const int nhw    = (gridDim.x * blockDim.x) >> 5;
    const float4 w0 = *(const float4*)(wrel + 0 * DIM + lane32 * 4);
    const float4 w1 = *(const float4*)(wrel + 1 * DIM + lane32 * 4);
    const float4 w2 = *(const float4*)(wrel + 2 * DIM + lane32 * 4);
    const float4 w3 = *(const float4*)(wrel + 3 * DIM + lane32 * 4);
    float wc[16];
#pragma unroll
    for (int i = 0; i < 16; ++i) wc[i] = wcls[i];
    float4 wf[4];
#pragma unroll
    for (int j = 0; j < 4; ++j) {
        wf[j].x = wc[j] * w0.x + wc[4 + j] * w1.x + wc[8 + j] * w2.x + wc[12 + j] * w3.x;
        wf[j].y = wc[j] * w0.y + wc[4 + j] * w1.y + wc[8 + j] * w2.y + wc[12 + j] * w3.y;
        wf[j].z = wc[j] * w0.z + wc[4 + j] * w1.z + wc[8 + j] * w2.z + wc[12 + j] * w3.z;
        wf[j].w = wc[j] * w0.w + wc[4 + j] * w1.w + wc[8 + j] * w2.w + wc[12 + j] * w3.w;
    }
    const int cls   = ((lane32 & 1) << 1) | ((lane32 >> 1) & 1);
    const int lelem = lane32 * 4;
    for (int e = hw; e < nEdges; e += nhw) {
        const float4 r = *(const float4*)(rna  + (size_t)ridx[e] * DIM + lelem);
        const float4 p = *(const float4*)(prot + (size_t)pidx[e] * DIM + lelem);
        float qx = r.x * p.x, qy = r.y * p.y, qz = r.z * p.z, qw = r.w * p.w;
        float b0 = qx * wf[0].x + qy * wf[0].y + qz * wf[0].z + qw * wf[0].w;
        float b1 = qx * wf[1].x + qy * wf[1].y + qz * wf[1].z + qw * wf[1].w;
        float b2 = qx * wf[2].x + qy * wf[2].y + qz * wf[2].z + qw * wf[2].w;
        float b3 = qx * wf[3].x + qy * wf[3].y + qz * wf[3].z + qw * wf[3].w;
        const float v = reduce4(b0, b1, b2, b3, lane32);
        if (lane32 < 4) out[(size_t)e * NCLS + cls] = fmaxf(v, 0.0f);
    }
}

extern "C" void kernel_launch(void* const* d_in, const int* in_sizes, int n_in,
                              void* d_out, int out_size, void* d_ws, size_t ws_size,
                              hipStream_t stream) {
    const float* rna  = (const float*)d_in[0];
    const float* prot = (const float*)d_in[1];
    const int*   ridx = (const int*)d_in[2];
    const int*   pidx = (const int*)d_in[3];
    const float* wrel = (const float*)d_in[4];
    const float* wcls = (const float*)d_in[5];
    float*       out  = (float*)d_out;

    const int nRnaElems  = in_sizes[0];   // 20000*128
    const int nProtElems = in_sizes[1];   // 5000*128
    const int nEdges     = in_sizes[2];   // 500000

    const size_t rnaBytes  = (size_t)nRnaElems * 2;
    const size_t needBytes = rnaBytes + (size_t)nProtElems * 2;

    if (ws_size >= needBytes && nEdges >= 4 &&
        (nRnaElems % 8) == 0 && (nProtElems % 8) == 0) {
        _Float16* rnaH  = (_Float16*)d_ws;
        _Float16* protH = (_Float16*)((char*)d_ws + rnaBytes);

        const int totalElems = nRnaElems + nProtElems;
        const int cvtBlocks  = (totalElems / 8 + 255) / 256;
        hipLaunchKernelGGL(cvt_both_kernel, dim3(cvtBlocks), dim3(256), 0, stream,
                           rna, rnaH, nRnaElems, prot, protH, nProtElems);

        // 2048 blocks; launch_bounds(256,4) -> VGPR cap 128, 16 waves/CU;
        // 24 row loads in flight per half-wave pair -> ~384 outstanding/CU.
        hipLaunchKernelGGL(decoder_ilp12_kernel, dim3(2048), dim3(256), 0, stream,
                           rnaH, protH, ridx, pidx, wrel, wcls, out, nEdges);
    } else {
        hipLaunchKernelGGL(decoder_f32_kernel, dim3(8192), dim3(256), 0, stream,
                           rna, prot, ridx, pidx, wrel, wcls, out, nEdges);
    }
}